// Round 5
// baseline (609.530 us; speedup 1.0000x reference)
//
#include <hip/hip_runtime.h>

#define B_ 8
#define C_ 128
#define WH_ 2304
#define N_ 8192

typedef unsigned short u16;
typedef float f32x4 __attribute__((ext_vector_type(4)));
typedef short s16x8 __attribute__((ext_vector_type(8)));

typedef const unsigned int __attribute__((address_space(1))) ga_u32;
typedef unsigned int __attribute__((address_space(3))) lds_u32;

#define LOG2E 1.4426950408889634f
#define MOFF  64.0f   // fixed softmax offset in log2 domain (no running max)

__device__ __forceinline__ float bf2f(u16 u){
    union { unsigned int i; float f; } x; x.i = ((unsigned int)u) << 16; return x.f;
}
__device__ __forceinline__ u16 f2bf(float f){
    union { float f; unsigned int i; } x; x.f = f;
    unsigned int r = x.i + 0x7fffu + ((x.i >> 16) & 1u);
    return (u16)(r >> 16);
}
// element index inside a [rows][128] bf16 LDS tile with 16B-block xor swizzle
__device__ __forceinline__ int swz(int row, int col){
    return row*128 + ((((col >> 3) ^ (row & 15)) << 3) | (col & 7));
}
__device__ __forceinline__ f32x4 fzero(){ f32x4 z = {0.f, 0.f, 0.f, 0.f}; return z; }
__device__ __forceinline__ f32x4 mfma16(s16x8 a, s16x8 b, f32x4 c){
    return __builtin_amdgcn_mfma_f32_16x16x32_bf16(a, b, c, 0, 0, 0);
}
__device__ __forceinline__ void gld16(const void* g, void* l){
    __builtin_amdgcn_global_load_lds((ga_u32*)g, (lds_u32*)l, 16, 0, 0);
}
__device__ __forceinline__ s16x8 ldsf(const u16* p){ return *(const s16x8*)p; }
__device__ __forceinline__ s16x8 cvt8(const float* p){
    s16x8 r;
    #pragma unroll
    for (int j = 0; j < 8; j++) r[j] = (short)f2bf(p[j]);
    return r;
}

// ---------------- K0: weights -> bf16 transposed [out][in] ----------------
__global__ __launch_bounds__(256) void k_prep(
    const float* __restrict__ Wq, const float* __restrict__ Wk,
    const float* __restrict__ Wv, const float* __restrict__ Wo,
    const float* __restrict__ Wg, u16* __restrict__ Wt)
{
    const int gid = blockIdx.x*256 + threadIdx.x;     // 5*16384
    const int mi = gid >> 14, e = gid & 16383;
    const int o = e >> 7, i = e & 127;
    const float* src = (mi==0)?Wq:(mi==1)?Wk:(mi==2)?Wv:(mi==3)?Wo:Wg;
    Wt[mi*16384 + o*128 + i] = f2bf(src[i*128 + o]);
}

// ---------------- K1a: pk/pv projection, 256-row tiles, weights in LDS ----------
__global__ __launch_bounds__(256) void k_proj_kv(
    const float* __restrict__ feat1,
    const float* __restrict__ bk, const float* __restrict__ bv,
    const u16* __restrict__ Wt,
    u16* __restrict__ Kb, u16* __restrict__ Vb)
{
    __shared__ __attribute__((aligned(16))) char smem[65536 + 66048];
    u16* Wks = (u16*)smem;              // [128][128] swz
    u16* Wvs = (u16*)(smem + 32768);
    u16* Af  = (u16*)(smem + 65536);    // [256][128] swz; later Ko / Tv staging
    const int t = threadIdx.x;
    const int b = blockIdx.x >> 5;
    const int n0 = (blockIdx.x & 31) * 256;
    for (int idx = t; idx < 2048; idx += 256){
        int o = idx >> 4, i0 = (idx & 15) << 3;
        *(s16x8*)&Wks[o*128 + (((i0 >> 3) ^ (o & 15)) << 3)] = *(const s16x8*)&Wt[16384 + o*128 + i0];
        *(s16x8*)&Wvs[o*128 + (((i0 >> 3) ^ (o & 15)) << 3)] = *(const s16x8*)&Wt[32768 + o*128 + i0];
    }
    for (int idx = t; idx < 256*128; idx += 256){
        int nl = idx & 255, c = idx >> 8;          // lanes -> nl consecutive (coalesced)
        Af[swz(nl, c)] = f2bf(feat1[((size_t)b*C_ + c)*N_ + n0 + nl]);
    }
    __syncthreads();
    const int lane = t & 63, w = t >> 6, qq = lane >> 4, m = lane & 15;
    s16x8 aA[4][4];
    #pragma unroll
    for (int rt = 0; rt < 4; rt++){
        const int ar = w*64 + rt*16 + m;
        #pragma unroll
        for (int kt = 0; kt < 4; kt++)
            aA[rt][kt] = ldsf(&Af[ar*128 + (((kt*4 + qq) ^ (ar & 15)) << 3)]);
    }
    f32x4 acc[4][8];
    // ---- K GEMM ----
    #pragma unroll
    for (int rt = 0; rt < 4; rt++){
        #pragma unroll
        for (int ct = 0; ct < 8; ct++) acc[rt][ct] = fzero();
    }
    #pragma unroll
    for (int kt = 0; kt < 4; kt++){
        #pragma unroll
        for (int ct = 0; ct < 8; ct++){
            const int bn = ct*16 + m;
            const s16x8 bf = ldsf(&Wks[bn*128 + (((kt*4 + qq) ^ (bn & 15)) << 3)]);
            #pragma unroll
            for (int rt = 0; rt < 4; rt++) acc[rt][ct] = mfma16(aA[rt][kt], bf, acc[rt][ct]);
        }
    }
    __syncthreads();                   // Af fragment reads complete
    u16* Ko = (u16*)(smem + 65536);    // [256][128] swz staging
    #pragma unroll
    for (int ct = 0; ct < 8; ct++){
        const int col = ct*16 + m;
        const float bkv = bk[col];
        #pragma unroll
        for (int rt = 0; rt < 4; rt++){
            #pragma unroll
            for (int i = 0; i < 4; i++)
                Ko[swz(w*64 + rt*16 + qq*4 + i, col)] = f2bf(acc[rt][ct][i] + bkv);
        }
    }
    #pragma unroll
    for (int j = 0; j < 16; j++){      // wave-private readback, coalesced store
        const int chunk = j*64 + lane;
        const int row = w*64 + (chunk >> 4);
        const int cb = chunk & 15;
        s16x8 v = ldsf(&Ko[row*128 + ((cb ^ (row & 15)) << 3)]);
        *(s16x8*)&Kb[((size_t)b*N_ + n0 + row)*C_ + cb*8] = v;
    }
    // ---- V GEMM (reuse acc) ----
    #pragma unroll
    for (int rt = 0; rt < 4; rt++){
        #pragma unroll
        for (int ct = 0; ct < 8; ct++) acc[rt][ct] = fzero();
    }
    #pragma unroll
    for (int kt = 0; kt < 4; kt++){
        #pragma unroll
        for (int ct = 0; ct < 8; ct++){
            const int bn = ct*16 + m;
            const s16x8 bf = ldsf(&Wvs[bn*128 + (((kt*4 + qq) ^ (bn & 15)) << 3)]);
            #pragma unroll
            for (int rt = 0; rt < 4; rt++) acc[rt][ct] = mfma16(aA[rt][kt], bf, acc[rt][ct]);
        }
    }
    __syncthreads();                   // Ko reads complete
    u16* Tv = (u16*)(smem + 65536);    // [128][258]
    #pragma unroll
    for (int ct = 0; ct < 8; ct++){
        const int col = ct*16 + m;
        const float bvv = bv[col];
        #pragma unroll
        for (int rt = 0; rt < 4; rt++){
            #pragma unroll
            for (int i = 0; i < 4; i++)
                Tv[col*258 + w*64 + rt*16 + qq*4 + i] = f2bf(acc[rt][ct][i] + bvv);
        }
    }
    __syncthreads();
    for (int idx = t; idx < 128*256; idx += 256){
        int c = idx >> 8, nl = idx & 255;
        Vb[((size_t)b*C_ + c)*N_ + n0 + nl] = Tv[c*258 + nl];
    }
}

// ---------------- K1b: pq/geo projection + gate, 128-row tiles ----------------
__global__ __launch_bounds__(256) void k_proj_qg(
    const float* __restrict__ feat0, const float* __restrict__ geo,
    const float* __restrict__ bq, const float* __restrict__ bg,
    const float* __restrict__ Wgate, const float* __restrict__ bgate,
    const u16* __restrict__ Wt,
    u16* __restrict__ Qb, u16* __restrict__ Gb)
{
    __shared__ __attribute__((aligned(16))) char smem[65536 + 32768];
    u16* Wqs = (u16*)smem;
    u16* Wgs = (u16*)(smem + 32768);
    u16* Aq  = (u16*)(smem + 65536);   // [128][128] swz; later store staging
    const int t = threadIdx.x;
    const int b = blockIdx.x / 18;
    const int r0 = (blockIdx.x % 18) * 128;
    for (int idx = t; idx < 2048; idx += 256){
        int o = idx >> 4, i0 = (idx & 15) << 3;
        *(s16x8*)&Wqs[o*128 + (((i0 >> 3) ^ (o & 15)) << 3)] = *(const s16x8*)&Wt[o*128 + i0];
        *(s16x8*)&Wgs[o*128 + (((i0 >> 3) ^ (o & 15)) << 3)] = *(const s16x8*)&Wt[65536 + o*128 + i0];
    }
    for (int idx = t; idx < 128*128; idx += 256){
        int r = idx & 127, c = idx >> 7;           // lanes -> r consecutive (coalesced)
        Aq[swz(r, c)] = f2bf(feat0[((size_t)b*C_ + c)*WH_ + r0 + r]);
    }
    __syncthreads();
    const int lane = t & 63, w = t >> 6, qq = lane >> 4, m = lane & 15;
    s16x8 aQ[2][4], aG[2][4];
    #pragma unroll
    for (int rt = 0; rt < 2; rt++){
        const int ar = w*32 + rt*16 + m;
        #pragma unroll
        for (int kt = 0; kt < 4; kt++){
            aQ[rt][kt] = ldsf(&Aq[ar*128 + (((kt*4 + qq) ^ (ar & 15)) << 3)]);
            aG[rt][kt] = cvt8(&geo[((size_t)b*WH_ + r0 + ar)*C_ + kt*32 + qq*8]);
        }
    }
    f32x4 accq[2][8], accg[2][8];
    #pragma unroll
    for (int rt = 0; rt < 2; rt++){
        #pragma unroll
        for (int ct = 0; ct < 8; ct++){ accq[rt][ct] = fzero(); accg[rt][ct] = fzero(); }
    }
    #pragma unroll
    for (int kt = 0; kt < 4; kt++){
        #pragma unroll
        for (int ct = 0; ct < 8; ct++){
            const int bn = ct*16 + m;
            const s16x8 b1 = ldsf(&Wqs[bn*128 + (((kt*4 + qq) ^ (bn & 15)) << 3)]);
            const s16x8 b2 = ldsf(&Wgs[bn*128 + (((kt*4 + qq) ^ (bn & 15)) << 3)]);
            #pragma unroll
            for (int rt = 0; rt < 2; rt++){
                accq[rt][ct] = mfma16(aQ[rt][kt], b1, accq[rt][ct]);
                accg[rt][ct] = mfma16(aG[rt][kt], b2, accg[rt][ct]);
            }
        }
    }
    float bqv[8], bgv[8], w1v[8], w2v[8];
    #pragma unroll
    for (int ct = 0; ct < 8; ct++){
        int col = ct*16 + m;
        bqv[ct] = bq[col]; bgv[ct] = bg[col];
        w1v[ct] = Wgate[col]; w2v[ct] = Wgate[C_ + col];
    }
    const float bg0 = bgate[0];
    float gate[2][4];
    #pragma unroll
    for (int rt = 0; rt < 2; rt++){
        #pragma unroll
        for (int i = 0; i < 4; i++){
            float p = 0.f;
            #pragma unroll
            for (int ct = 0; ct < 8; ct++)
                p += (accq[rt][ct][i] + bqv[ct]) * w1v[ct] + (accg[rt][ct][i] + bgv[ct]) * w2v[ct];
            #pragma unroll
            for (int off = 1; off < 16; off <<= 1) p += __shfl_xor(p, off, 64);
            gate[rt][i] = 1.f / (1.f + __expf(-(p + bg0)));
        }
    }
    __syncthreads();                 // Aq fragment reads complete
    u16* St = Aq;                    // [128][128] swz staging
    #pragma unroll
    for (int ct = 0; ct < 8; ct++){
        #pragma unroll
        for (int rt = 0; rt < 2; rt++){
            #pragma unroll
            for (int i = 0; i < 4; i++){
                const float ge = accg[rt][ct][i] + bgv[ct];
                const float pq = accq[rt][ct][i] + bqv[ct] + gate[rt][i] * ge;
                St[swz(w*32 + rt*16 + qq*4 + i, ct*16 + m)] = f2bf(pq * LOG2E);
            }
        }
    }
    #pragma unroll
    for (int j = 0; j < 8; j++){
        const int chunk = j*64 + lane;
        const int row = w*32 + (chunk >> 4);
        const int cb = chunk & 15;
        s16x8 v = ldsf(&St[row*128 + ((cb ^ (row & 15)) << 3)]);
        *(s16x8*)&Qb[((size_t)b*WH_ + r0 + row)*C_ + cb*8] = v;
    }
    #pragma unroll
    for (int ct = 0; ct < 8; ct++){
        #pragma unroll
        for (int rt = 0; rt < 2; rt++){
            #pragma unroll
            for (int i = 0; i < 4; i++)
                St[swz(w*32 + rt*16 + qq*4 + i, ct*16 + m)] = f2bf(accg[rt][ct][i] + bgv[ct]);
        }
    }
    #pragma unroll
    for (int j = 0; j < 8; j++){
        const int chunk = j*64 + lane;
        const int row = w*32 + (chunk >> 4);
        const int cb = chunk & 15;
        s16x8 v = ldsf(&St[row*128 + ((cb ^ (row & 15)) << 3)]);
        *(s16x8*)&Gb[((size_t)b*WH_ + r0 + row)*C_ + cb*8] = v;
    }
}

// ---------------- K2: flash attention, lockstep chunk permutation ----------------
__global__ __launch_bounds__(512, 1) void k_flash(
    const u16* __restrict__ Qb, const u16* __restrict__ Kb, const u16* __restrict__ Vb,
    u16* __restrict__ Opart, float* __restrict__ Lp)
{
    __shared__ __attribute__((aligned(16))) u16 KP[128*128];   // K tile   (32 KB)
    __shared__ __attribute__((aligned(16))) u16 Vt[128*128];   // V^T tile (32 KB)
    __shared__ __attribute__((aligned(16))) u16 Pb[8*32*128];  // per-wave P (64 KB)
    const int t = threadIdx.x;
    const int lane = t & 63, w = t >> 6;            // 8 waves
    const int q = lane >> 4, m = lane & 15;
    const int rw = w * 32;
    const int b = blockIdx.x & 7;                   // XCD affinity: batch == blockIdx%8
    const int s = blockIdx.x >> 3;                  // slot 0..31 within batch
    u16* Pw = &Pb[w * 4096];

    s16x8 ONES;
    #pragma unroll
    for (int j = 0; j < 8; j++) ONES[j] = (short)0x3F80;  // bf16 1.0

    int u = s * 18;
    const int uend = u + 18;
    while (u < uend){
        const int qb = u >> 6;                      // q-tile (256 rows) within batch
        const int l0 = u & 63;
        int lN = uend - u; { int rem = 64 - l0; if (lN > rem) lN = rem; }
        const int a = (qb * 64) % 18;               // step phase of this q-tile
        const size_t qrow0 = (size_t)b*WH_ + qb*256;

        s16x8 qf[2][4];
        #pragma unroll
        for (int rt = 0; rt < 2; rt++){
            #pragma unroll
            for (int kt = 0; kt < 4; kt++)
                qf[rt][kt] = *(const s16x8*)&Qb[(qrow0 + rw + rt*16 + m)*C_ + kt*32 + q*8];
        }
        f32x4 o[2][8], ol[2];
        #pragma unroll
        for (int rt = 0; rt < 2; rt++){
            ol[rt] = fzero();
            #pragma unroll
            for (int ct = 0; ct < 8; ct++) o[rt][ct] = fzero();
        }

        for (int l = l0; l < l0 + lN; l++){
            // chunk permutation: rank of l under key ((a+l)%18, l)  ->  all slots
            // in a batch process chunk ci ~= 64*T/18 at the same wall-step T.
            const int T = (a + l) % 18;
            int rnk = 0;
            for (int tt = 0; tt < T; ++tt) rnk += 1 + (63 - ((tt - a + 36) % 18)) / 18;
            const int ci = rnk + l / 18;
            const int n0 = ci * 128;
            __syncthreads();   // all waves done with prev K/V
            #pragma unroll
            for (int j = 0; j < 4; j++){
                const int r = w*16 + j*4 + (lane >> 4);   // K row / V channel
                gld16(Kb + ((size_t)b*N_ + n0 + r)*C_ + ((m ^ (r & 15)) << 3),
                      &KP[(w*16 + j*4)*128]);
                gld16(Vb + ((size_t)b*C_ + r)*N_ + n0 + ((m ^ (r & 15)) << 3),
                      &Vt[(w*16 + j*4)*128]);
            }
            __syncthreads();   // K/V visible
            f32x4 sA[2][8];
            #pragma unroll
            for (int rt = 0; rt < 2; rt++){
                #pragma unroll
                for (int ct = 0; ct < 8; ct++) sA[rt][ct] = fzero();
            }
            #pragma unroll
            for (int kt = 0; kt < 4; kt++){
                #pragma unroll
                for (int ct = 0; ct < 8; ct++){
                    const int bn = ct*16 + m;
                    s16x8 kf = ldsf(&KP[bn*128 + (((kt*4 + q) ^ (bn & 15)) << 3)]);
                    sA[0][ct] = mfma16(qf[0][kt], kf, sA[0][ct]);
                    sA[1][ct] = mfma16(qf[1][kt], kf, sA[1][ct]);
                }
            }
            // fixed-offset softmax: p = 2^(s' - MOFF); no reductions, no barrier
            #pragma unroll
            for (int rt = 0; rt < 2; rt++){
                #pragma unroll
                for (int i = 0; i < 4; i++){
                    const int row = rt*16 + q*4 + i;
                    #pragma unroll
                    for (int ct = 0; ct < 8; ct++)
                        Pw[swz(row, ct*16 + m)] = f2bf(exp2f(sA[rt][ct][i] - MOFF));
                }
            }
            // PV + row-sum via ones-column (wave-private P)
            #pragma unroll
            for (int kt = 0; kt < 4; kt++){
                s16x8 p0 = ldsf(&Pw[m*128        + (((kt*4 + q) ^ m) << 3)]);
                s16x8 p1 = ldsf(&Pw[(16 + m)*128 + (((kt*4 + q) ^ m) << 3)]);
                #pragma unroll
                for (int ct = 0; ct < 8; ct++){
                    const int cc = ct*16 + m;
                    s16x8 vf = ldsf(&Vt[cc*128 + (((kt*4 + q) ^ (cc & 15)) << 3)]);
                    o[0][ct] = mfma16(p0, vf, o[0][ct]);
                    o[1][ct] = mfma16(p1, vf, o[1][ct]);
                }
                ol[0] = mfma16(p0, ONES, ol[0]);
                ol[1] = mfma16(p1, ONES, ol[1]);
            }
        }
        // flush partials for this q-tile: LDS round-trip -> coalesced 16B stores
        const int sf = (qb * 64) / 18;
        const size_t pbase = ((size_t)(b*9 + qb)*5 + (s - sf)) * 256;
        #pragma unroll
        for (int rt = 0; rt < 2; rt++){
            #pragma unroll
            for (int i = 0; i < 4; i++){
                const int row = rt*16 + q*4 + i;
                #pragma unroll
                for (int ct = 0; ct < 8; ct++)
                    Pw[swz(row, ct*16 + m)] = f2bf(o[rt][ct][i]);
            }
        }
        #pragma unroll
        for (int j = 0; j < 8; j++){
            const int chunk = j*64 + lane;
            const int row = chunk >> 4;       // 0..31 (wave-local)
            const int cb = chunk & 15;
            s16x8 v = ldsf(&Pw[row*128 + ((cb ^ (row & 15)) << 3)]);
            *(s16x8*)&Opart[(pbase + rw + row)*128 + cb*8] = v;
        }
        if (m == 0){
            #pragma unroll
            for (int rt = 0; rt < 2; rt++){
                #pragma unroll
                for (int i = 0; i < 4; i++)
                    Lp[pbase + rw + rt*16 + q*4 + i] = ol[rt][i];
            }
        }
        u += lN;
    }
}

// ---------------- K3: combine partials, @Wo+bo, geo-gate, +feat0, transpose --------
__global__ __launch_bounds__(256) void k_out(
    const u16* __restrict__ Opart, const float* __restrict__ Lp,
    const float* __restrict__ bo, const u16* __restrict__ Wt,
    const u16* __restrict__ Gb, const float* __restrict__ feat0,
    float* __restrict__ outp)
{
    __shared__ __attribute__((aligned(16))) u16 AO[128*128];   // 32 KB
    __shared__ u16 Tr[128*130];                                 // 33.3 KB
    const int t = threadIdx.x;
    const int bqt = blockIdx.x;                 // 0..143 (half q-tiles of 128 rows)
    const int qt2 = bqt >> 1, half = bqt & 1;
    const int b = qt2 / 9, qb = qt2 % 9;
    const int gr0 = qb*256 + half*128;          // row base within batch
    const u16* WoT = Wt + 49152;
    const float rsC = 0.088388347648318447f;    // 1/sqrt(128)
    const int sf = (qb*64) / 18;
    const int sl = (qb*64 + 63) / 18;
    const int cnt = sl - sf + 1;
    for (int idx = t; idx < 128*128; idx += 256){
        int r = idx >> 7, c = idx & 127;
        float num = 0.f, den = 0.f;
        for (int ss = 0; ss < cnt; ss++){
            const size_t base = ((size_t)qt2*5 + ss)*256 + half*128 + r;
            num += bf2f(Opart[base*128 + c]);
            den += Lp[base];
        }
        AO[swz(r, c)] = f2bf(num / den * rsC);
    }
    __syncthreads();
    const int lane = t & 63, w = t >> 6;
    const int q = lane >> 4, m = lane & 15;
    const int rw = w * 32;
    f32x4 acc[2][8];
    #pragma unroll
    for (int rt = 0; rt < 2; rt++){
        #pragma unroll
        for (int ct = 0; ct < 8; ct++) acc[rt][ct] = fzero();
    }
    #pragma unroll
    for (int kt = 0; kt < 4; kt++){
        s16x8 a0, a1;
        { const int ar = rw + m;      a0 = ldsf(&AO[ar*128 + (((kt*4 + q) ^ (ar & 15)) << 3)]); }
        { const int ar = rw + 16 + m; a1 = ldsf(&AO[ar*128 + (((kt*4 + q) ^ (ar & 15)) << 3)]); }
        #pragma unroll
        for (int ct = 0; ct < 8; ct++){
            const s16x8 bb = *(const s16x8*)&WoT[(ct*16 + m)*128 + kt*32 + q*8];
            acc[0][ct] = mfma16(a0, bb, acc[0][ct]);
            acc[1][ct] = mfma16(a1, bb, acc[1][ct]);
        }
    }
    #pragma unroll
    for (int ct = 0; ct < 8; ct++){
        const int col = ct*16 + m;
        const float bov = bo[col];
        #pragma unroll
        for (int rt = 0; rt < 2; rt++){
            #pragma unroll
            for (int i = 0; i < 4; i++){
                const int rl = rw + rt*16 + q*4 + i;
                const float gv = bf2f(Gb[((size_t)b*WH_ + gr0 + rl)*C_ + col]);
                const float sg = 1.f / (1.f + __expf(-gv));
                Tr[rl*130 + col] = f2bf((acc[rt][ct][i] + bov) * (1.f + sg));
            }
        }
    }
    __syncthreads();
    for (int idx = t; idx < 128*128; idx += 256){
        int c = idx >> 7, wh = idx & 127;
        float v = bf2f(Tr[wh*130 + c]) + feat0[(size_t)(b*C_ + c)*WH_ + gr0 + wh];
        outp[(size_t)(b*C_ + c)*WH_ + gr0 + wh] = v;
    }
}

extern "C" void kernel_launch(void* const* d_in, const int* in_sizes, int n_in,
                              void* d_out, int out_size, void* d_ws, size_t ws_size,
                              hipStream_t stream)
{
    (void)in_sizes; (void)n_in; (void)out_size; (void)ws_size;
    const float* feat0 = (const float*)d_in[0];
    const float* feat1 = (const float*)d_in[1];
    const float* geo   = (const float*)d_in[2];
    const float* Wq = (const float*)d_in[3];  const float* bq = (const float*)d_in[4];
    const float* Wk = (const float*)d_in[5];  const float* bk = (const float*)d_in[6];
    const float* Wv = (const float*)d_in[7];  const float* bv = (const float*)d_in[8];
    const float* Wo = (const float*)d_in[9];  const float* bo = (const float*)d_in[10];
    const float* Wg = (const float*)d_in[11]; const float* bg = (const float*)d_in[12];
    const float* Wgate = (const float*)d_in[13]; const float* bgate = (const float*)d_in[14];
    float* outp = (float*)d_out;
    char* ws = (char*)d_ws;
    size_t off = 0;
    auto alloc = [&](size_t bytes) -> void* {
        void* p = (void*)(ws + off);
        off += (bytes + 255) & ~(size_t)255;
        return p;
    };
    u16* Qb = (u16*)alloc((size_t)B_*WH_*C_*2);         // pq (gated, x log2e)
    u16* Gb = (u16*)alloc((size_t)B_*WH_*C_*2);         // geo proj
    u16* Kb = (u16*)alloc((size_t)B_*N_*C_*2);          // pk [b][n][c]
    u16* Vb = (u16*)alloc((size_t)B_*N_*C_*2);          // pv^T [b][c][n]
    u16* Opart = (u16*)alloc((size_t)72*5*256*128*2);   // flash partials
    float* Lp  = (float*)alloc((size_t)72*5*256*4);     // partial row sums
    u16* Wt = (u16*)alloc((size_t)5*16384*2);           // bf16 transposed weights

    k_prep   <<<dim3(320), dim3(256), 0, stream>>>(Wq, Wk, Wv, Wo, Wg, Wt);
    k_proj_kv<<<dim3(256), dim3(256), 0, stream>>>(feat1, bk, bv, Wt, Kb, Vb);
    k_proj_qg<<<dim3(144), dim3(256), 0, stream>>>(feat0, geo, bq, bg, Wgate, bgate, Wt, Qb, Gb);
    k_flash  <<<dim3(256), dim3(512), 0, stream>>>(Qb, Kb, Vb, Opart, Lp);
    k_out    <<<dim3(144), dim3(256), 0, stream>>>(Opart, Lp, bo, Wt, Gb, feat0, outp);
}

// Round 7
// 369.805 us; speedup vs baseline: 1.6482x; 1.6482x over previous
//
#include <hip/hip_runtime.h>

#define B_ 8
#define C_ 128
#define WH_ 2304
#define N_ 8192

typedef unsigned short u16;
typedef float f32x4 __attribute__((ext_vector_type(4)));
typedef short s16x8 __attribute__((ext_vector_type(8)));
typedef short s16x4 __attribute__((ext_vector_type(4)));
typedef unsigned int u32x2 __attribute__((ext_vector_type(2)));

typedef const unsigned int __attribute__((address_space(1))) ga_u32;
typedef unsigned int __attribute__((address_space(3))) lds_u32;

#define LOG2E 1.4426950408889634f
#define MOFF  64.0f   // fixed softmax offset in log2 domain (no running max)

// K=16 bf16 MFMA (v_mfma_f32_16x16x16_bf16 on gfx950; gfx90a-lineage builtin).
// NOTE: do NOT gate on __has_builtin — it returns false on the HIP host pass.
#define MFMA16K16(a,b,c) __builtin_amdgcn_mfma_f32_16x16x16bf16_1k(a,b,c,0,0,0)

__device__ __forceinline__ float bf2f(u16 u){
    union { unsigned int i; float f; } x; x.i = ((unsigned int)u) << 16; return x.f;
}
__device__ __forceinline__ u16 f2bf(float f){
    union { float f; unsigned int i; } x; x.f = f;
    unsigned int r = x.i + 0x7fffu + ((x.i >> 16) & 1u);
    return (u16)(r >> 16);
}
// element index inside a [rows][128] bf16 LDS tile with 16B-block xor swizzle
__device__ __forceinline__ int swz(int row, int col){
    return row*128 + ((((col >> 3) ^ (row & 15)) << 3) | (col & 7));
}
__device__ __forceinline__ f32x4 fzero(){ f32x4 z = {0.f, 0.f, 0.f, 0.f}; return z; }
__device__ __forceinline__ f32x4 mfma16(s16x8 a, s16x8 b, f32x4 c){
    return __builtin_amdgcn_mfma_f32_16x16x32_bf16(a, b, c, 0, 0, 0);
}
__device__ __forceinline__ void gld16(const void* g, void* l){
    __builtin_amdgcn_global_load_lds((ga_u32*)g, (lds_u32*)l, 16, 0, 0);
}
__device__ __forceinline__ s16x8 ldsf(const u16* p){ return *(const s16x8*)p; }
__device__ __forceinline__ s16x4 ldsf4(const u16* p){ return *(const s16x4*)p; }
__device__ __forceinline__ s16x8 cvt8(const float* p){
    s16x8 r;
    #pragma unroll
    for (int j = 0; j < 8; j++) r[j] = (short)f2bf(p[j]);
    return r;
}

// ---------------- K0: weights -> bf16 transposed [out][in] ----------------
__global__ __launch_bounds__(256) void k_prep(
    const float* __restrict__ Wq, const float* __restrict__ Wk,
    const float* __restrict__ Wv, const float* __restrict__ Wo,
    const float* __restrict__ Wg, u16* __restrict__ Wt)
{
    const int gid = blockIdx.x*256 + threadIdx.x;     // 5*16384
    const int mi = gid >> 14, e = gid & 16383;
    const int o = e >> 7, i = e & 127;
    const float* src = (mi==0)?Wq:(mi==1)?Wk:(mi==2)?Wv:(mi==3)?Wo:Wg;
    Wt[mi*16384 + o*128 + i] = f2bf(src[i*128 + o]);
}

// ---------------- K1a: pk/pv projection, 256-row tiles, weights in LDS ----------
__global__ __launch_bounds__(256) void k_proj_kv(
    const float* __restrict__ feat1,
    const float* __restrict__ bk, const float* __restrict__ bv,
    const u16* __restrict__ Wt,
    u16* __restrict__ Kb, u16* __restrict__ Vb)
{
    __shared__ __attribute__((aligned(16))) char smem[65536 + 66048];
    u16* Wks = (u16*)smem;              // [128][128] swz
    u16* Wvs = (u16*)(smem + 32768);
    u16* Af  = (u16*)(smem + 65536);    // [256][128] swz; later Ko / Tv staging
    const int t = threadIdx.x;
    const int b = blockIdx.x >> 5;
    const int n0 = (blockIdx.x & 31) * 256;
    for (int idx = t; idx < 2048; idx += 256){
        int o = idx >> 4, i0 = (idx & 15) << 3;
        *(s16x8*)&Wks[o*128 + (((i0 >> 3) ^ (o & 15)) << 3)] = *(const s16x8*)&Wt[16384 + o*128 + i0];
        *(s16x8*)&Wvs[o*128 + (((i0 >> 3) ^ (o & 15)) << 3)] = *(const s16x8*)&Wt[32768 + o*128 + i0];
    }
    for (int idx = t; idx < 256*128; idx += 256){
        int nl = idx & 255, c = idx >> 8;          // lanes -> nl consecutive (coalesced)
        Af[swz(nl, c)] = f2bf(feat1[((size_t)b*C_ + c)*N_ + n0 + nl]);
    }
    __syncthreads();
    const int lane = t & 63, w = t >> 6, qq = lane >> 4, m = lane & 15;
    s16x8 aA[4][4];
    #pragma unroll
    for (int rt = 0; rt < 4; rt++){
        const int ar = w*64 + rt*16 + m;
        #pragma unroll
        for (int kt = 0; kt < 4; kt++)
            aA[rt][kt] = ldsf(&Af[ar*128 + (((kt*4 + qq) ^ (ar & 15)) << 3)]);
    }
    f32x4 acc[4][8];
    // ---- K GEMM ----
    #pragma unroll
    for (int rt = 0; rt < 4; rt++){
        #pragma unroll
        for (int ct = 0; ct < 8; ct++) acc[rt][ct] = fzero();
    }
    #pragma unroll
    for (int kt = 0; kt < 4; kt++){
        #pragma unroll
        for (int ct = 0; ct < 8; ct++){
            const int bn = ct*16 + m;
            const s16x8 bf = ldsf(&Wks[bn*128 + (((kt*4 + qq) ^ (bn & 15)) << 3)]);
            #pragma unroll
            for (int rt = 0; rt < 4; rt++) acc[rt][ct] = mfma16(aA[rt][kt], bf, acc[rt][ct]);
        }
    }
    __syncthreads();                   // Af fragment reads complete
    u16* Ko = (u16*)(smem + 65536);    // [256][128] swz staging
    #pragma unroll
    for (int ct = 0; ct < 8; ct++){
        const int col = ct*16 + m;
        const float bkv = bk[col];
        #pragma unroll
        for (int rt = 0; rt < 4; rt++){
            #pragma unroll
            for (int i = 0; i < 4; i++)
                Ko[swz(w*64 + rt*16 + qq*4 + i, col)] = f2bf(acc[rt][ct][i] + bkv);
        }
    }
    #pragma unroll
    for (int j = 0; j < 16; j++){      // wave-private readback, coalesced store
        const int chunk = j*64 + lane;
        const int row = w*64 + (chunk >> 4);
        const int cb = chunk & 15;
        s16x8 v = ldsf(&Ko[row*128 + ((cb ^ (row & 15)) << 3)]);
        *(s16x8*)&Kb[((size_t)b*N_ + n0 + row)*C_ + cb*8] = v;
    }
    // ---- V GEMM (reuse acc) ----
    #pragma unroll
    for (int rt = 0; rt < 4; rt++){
        #pragma unroll
        for (int ct = 0; ct < 8; ct++) acc[rt][ct] = fzero();
    }
    #pragma unroll
    for (int kt = 0; kt < 4; kt++){
        #pragma unroll
        for (int ct = 0; ct < 8; ct++){
            const int bn = ct*16 + m;
            const s16x8 bf = ldsf(&Wvs[bn*128 + (((kt*4 + qq) ^ (bn & 15)) << 3)]);
            #pragma unroll
            for (int rt = 0; rt < 4; rt++) acc[rt][ct] = mfma16(aA[rt][kt], bf, acc[rt][ct]);
        }
    }
    __syncthreads();                   // Ko reads complete
    u16* Tv = (u16*)(smem + 65536);    // [128][258]
    #pragma unroll
    for (int ct = 0; ct < 8; ct++){
        const int col = ct*16 + m;
        const float bvv = bv[col];
        #pragma unroll
        for (int rt = 0; rt < 4; rt++){
            #pragma unroll
            for (int i = 0; i < 4; i++)
                Tv[col*258 + w*64 + rt*16 + qq*4 + i] = f2bf(acc[rt][ct][i] + bvv);
        }
    }
    __syncthreads();
    for (int idx = t; idx < 128*256; idx += 256){
        int c = idx >> 8, nl = idx & 255;
        Vb[((size_t)b*C_ + c)*N_ + n0 + nl] = Tv[c*258 + nl];
    }
}

// ---------------- K1b: pq/geo projection + gate, 128-row tiles ----------------
__global__ __launch_bounds__(256) void k_proj_qg(
    const float* __restrict__ feat0, const float* __restrict__ geo,
    const float* __restrict__ bq, const float* __restrict__ bg,
    const float* __restrict__ Wgate, const float* __restrict__ bgate,
    const u16* __restrict__ Wt,
    u16* __restrict__ Qb, u16* __restrict__ Gb)
{
    __shared__ __attribute__((aligned(16))) char smem[65536 + 32768];
    u16* Wqs = (u16*)smem;
    u16* Wgs = (u16*)(smem + 32768);
    u16* Aq  = (u16*)(smem + 65536);   // [128][128] swz; later store staging
    const int t = threadIdx.x;
    const int b = blockIdx.x / 18;
    const int r0 = (blockIdx.x % 18) * 128;
    for (int idx = t; idx < 2048; idx += 256){
        int o = idx >> 4, i0 = (idx & 15) << 3;
        *(s16x8*)&Wqs[o*128 + (((i0 >> 3) ^ (o & 15)) << 3)] = *(const s16x8*)&Wt[o*128 + i0];
        *(s16x8*)&Wgs[o*128 + (((i0 >> 3) ^ (o & 15)) << 3)] = *(const s16x8*)&Wt[65536 + o*128 + i0];
    }
    for (int idx = t; idx < 128*128; idx += 256){
        int r = idx & 127, c = idx >> 7;           // lanes -> r consecutive (coalesced)
        Aq[swz(r, c)] = f2bf(feat0[((size_t)b*C_ + c)*WH_ + r0 + r]);
    }
    __syncthreads();
    const int lane = t & 63, w = t >> 6, qq = lane >> 4, m = lane & 15;
    s16x8 aQ[2][4], aG[2][4];
    #pragma unroll
    for (int rt = 0; rt < 2; rt++){
        const int ar = w*32 + rt*16 + m;
        #pragma unroll
        for (int kt = 0; kt < 4; kt++){
            aQ[rt][kt] = ldsf(&Aq[ar*128 + (((kt*4 + qq) ^ (ar & 15)) << 3)]);
            aG[rt][kt] = cvt8(&geo[((size_t)b*WH_ + r0 + ar)*C_ + kt*32 + qq*8]);
        }
    }
    f32x4 accq[2][8], accg[2][8];
    #pragma unroll
    for (int rt = 0; rt < 2; rt++){
        #pragma unroll
        for (int ct = 0; ct < 8; ct++){ accq[rt][ct] = fzero(); accg[rt][ct] = fzero(); }
    }
    #pragma unroll
    for (int kt = 0; kt < 4; kt++){
        #pragma unroll
        for (int ct = 0; ct < 8; ct++){
            const int bn = ct*16 + m;
            const s16x8 b1 = ldsf(&Wqs[bn*128 + (((kt*4 + qq) ^ (bn & 15)) << 3)]);
            const s16x8 b2 = ldsf(&Wgs[bn*128 + (((kt*4 + qq) ^ (bn & 15)) << 3)]);
            #pragma unroll
            for (int rt = 0; rt < 2; rt++){
                accq[rt][ct] = mfma16(aQ[rt][kt], b1, accq[rt][ct]);
                accg[rt][ct] = mfma16(aG[rt][kt], b2, accg[rt][ct]);
            }
        }
    }
    float bqv[8], bgv[8], w1v[8], w2v[8];
    #pragma unroll
    for (int ct = 0; ct < 8; ct++){
        int col = ct*16 + m;
        bqv[ct] = bq[col]; bgv[ct] = bg[col];
        w1v[ct] = Wgate[col]; w2v[ct] = Wgate[C_ + col];
    }
    const float bg0 = bgate[0];
    float gate[2][4];
    #pragma unroll
    for (int rt = 0; rt < 2; rt++){
        #pragma unroll
        for (int i = 0; i < 4; i++){
            float p = 0.f;
            #pragma unroll
            for (int ct = 0; ct < 8; ct++)
                p += (accq[rt][ct][i] + bqv[ct]) * w1v[ct] + (accg[rt][ct][i] + bgv[ct]) * w2v[ct];
            #pragma unroll
            for (int off = 1; off < 16; off <<= 1) p += __shfl_xor(p, off, 64);
            gate[rt][i] = 1.f / (1.f + __expf(-(p + bg0)));
        }
    }
    __syncthreads();                 // Aq fragment reads complete
    u16* St = Aq;                    // [128][128] swz staging
    #pragma unroll
    for (int ct = 0; ct < 8; ct++){
        #pragma unroll
        for (int rt = 0; rt < 2; rt++){
            #pragma unroll
            for (int i = 0; i < 4; i++){
                const float ge = accg[rt][ct][i] + bgv[ct];
                const float pq = accq[rt][ct][i] + bqv[ct] + gate[rt][i] * ge;
                St[swz(w*32 + rt*16 + qq*4 + i, ct*16 + m)] = f2bf(pq * LOG2E);
            }
        }
    }
    #pragma unroll
    for (int j = 0; j < 8; j++){
        const int chunk = j*64 + lane;
        const int row = w*32 + (chunk >> 4);
        const int cb = chunk & 15;
        s16x8 v = ldsf(&St[row*128 + ((cb ^ (row & 15)) << 3)]);
        *(s16x8*)&Qb[((size_t)b*WH_ + r0 + row)*C_ + cb*8] = v;
    }
    #pragma unroll
    for (int ct = 0; ct < 8; ct++){
        #pragma unroll
        for (int rt = 0; rt < 2; rt++){
            #pragma unroll
            for (int i = 0; i < 4; i++)
                St[swz(w*32 + rt*16 + qq*4 + i, ct*16 + m)] = f2bf(accg[rt][ct][i] + bgv[ct]);
        }
    }
    #pragma unroll
    for (int j = 0; j < 8; j++){
        const int chunk = j*64 + lane;
        const int row = w*32 + (chunk >> 4);
        const int cb = chunk & 15;
        s16x8 v = ldsf(&St[row*128 + ((cb ^ (row & 15)) << 3)]);
        *(s16x8*)&Gb[((size_t)b*WH_ + r0 + row)*C_ + cb*8] = v;
    }
}

// ---------------- K2: flash attention, double-buffered, S^T/O^T register path ----
__global__ __launch_bounds__(512, 1) void k_flash(
    const u16* __restrict__ Qb, const u16* __restrict__ Kb, const u16* __restrict__ Vb,
    u16* __restrict__ Opart, float* __restrict__ Lp)
{
    __shared__ __attribute__((aligned(16))) u16 KP0[128*128];   // 32 KB each
    __shared__ __attribute__((aligned(16))) u16 KP1[128*128];
    __shared__ __attribute__((aligned(16))) u16 Vt0[128*128];
    __shared__ __attribute__((aligned(16))) u16 Vt1[128*128];
    const int t = threadIdx.x;
    const int lane = t & 63, w = t >> 6;            // 8 waves
    const int q = lane >> 4, m = lane & 15;         // q = quad
    const int rw = w * 32;
    const int b = blockIdx.x & 7;
    const int s = blockIdx.x >> 3;                  // slot 0..31

    f32x4 o[8][2];
    float lr[2];
    s16x8 qf[2][4];

    auto issue = [&](int k){
        const int u = s*18 + k;
        const int n0 = (u & 63) * 128;              // sequential chunk order (round-3 pattern)
        u16* KPd = (k & 1) ? KP1 : KP0;
        u16* Vtd = (k & 1) ? Vt1 : Vt0;
        #pragma unroll
        for (int j = 0; j < 4; j++){
            const int r = w*16 + j*4 + q;           // K row / V channel (per-lane via DMA)
            gld16(Kb + ((size_t)b*N_ + n0 + r)*C_ + ((m ^ (r & 15)) << 3), &KPd[(w*16 + j*4)*128]);
            gld16(Vb + ((size_t)b*C_ + r)*N_ + n0 + ((m ^ (r & 15)) << 3), &Vtd[(w*16 + j*4)*128]);
        }
    };
    auto load_q = [&](int qb){
        const size_t qrow0 = (size_t)b*WH_ + qb*256;
        #pragma unroll
        for (int rt = 0; rt < 2; rt++){
            #pragma unroll
            for (int kt = 0; kt < 4; kt++)
                qf[rt][kt] = *(const s16x8*)&Qb[(qrow0 + rw + rt*16 + m)*C_ + kt*32 + q*8];
        }
    };
    auto zero_acc = [&](){
        #pragma unroll
        for (int ct = 0; ct < 8; ct++){ o[ct][0] = fzero(); o[ct][1] = fzero(); }
        lr[0] = 0.f; lr[1] = 0.f;
    };
    auto flush = [&](int qb){
        const int sf = (qb * 64) / 18;
        const size_t pbase = ((size_t)(b*9 + qb)*5 + (s - sf)) * 256;
        #pragma unroll
        for (int ct = 0; ct < 8; ct++){
            #pragma unroll
            for (int rt = 0; rt < 2; rt++){
                u32x2 pk;
                pk.x = (unsigned int)f2bf(o[ct][rt][0]) | ((unsigned int)f2bf(o[ct][rt][1]) << 16);
                pk.y = (unsigned int)f2bf(o[ct][rt][2]) | ((unsigned int)f2bf(o[ct][rt][3]) << 16);
                // O^T C-layout: lane holds rows c=ct*16+q*4+0..3, q-row col = m -> 8 B contiguous in c
                *(u32x2*)&Opart[(pbase + rw + rt*16 + m)*128 + ct*16 + q*4] = pk;
            }
        }
        float l0 = lr[0], l1 = lr[1];
        l0 += __shfl_xor(l0, 16, 64); l0 += __shfl_xor(l0, 32, 64);
        l1 += __shfl_xor(l1, 16, 64); l1 += __shfl_xor(l1, 32, 64);
        if (q == 0){
            Lp[pbase + rw + m] = l0;
            Lp[pbase + rw + 16 + m] = l1;
        }
    };

    issue(0);
    int cur_qb = (s*18) >> 6;
    load_q(cur_qb);
    zero_acc();

    for (int k = 0; k < 18; k++){
        __syncthreads();                 // drains prefetch(k) (a full compute-phase old) + buffer sync
        if (k < 17) issue(k + 1);        // overlaps with compute below
        const u16* KPc = (k & 1) ? KP1 : KP0;
        const u16* Vtc = (k & 1) ? Vt1 : Vt0;

        // S^T = K·Q^T ; exp'd C-layout fragment == B-layout for K=16 PV (no LDS round-trip)
        s16x4 pexp[8][2];
        #pragma unroll
        for (int nt = 0; nt < 8; nt++){
            f32x4 s0 = fzero(), s1 = fzero();
            const int bn = nt*16 + m;
            #pragma unroll
            for (int kt = 0; kt < 4; kt++){
                s16x8 kf = ldsf(&KPc[bn*128 + (((kt*4 + q) ^ (bn & 15)) << 3)]);
                s0 = mfma16(kf, qf[0][kt], s0);
                s1 = mfma16(kf, qf[1][kt], s1);
            }
            #pragma unroll
            for (int i = 0; i < 4; i++){
                float e0 = exp2f(s0[i] - MOFF);
                float e1 = exp2f(s1[i] - MOFF);
                lr[0] += e0; lr[1] += e1;
                pexp[nt][0][i] = (short)f2bf(e0);
                pexp[nt][1][i] = (short)f2bf(e1);
            }
        }
        // O^T += V^T · P^T   (K=16 mfma; A=V^T direct from Vt rows, B=pexp registers)
        #pragma unroll
        for (int ct = 0; ct < 8; ct++){
            const int cc = ct*16 + m;
            #pragma unroll
            for (int g = 0; g < 8; g++){
                s16x4 vf = ldsf4(&Vtc[cc*128 + ((((g*2 + (q >> 1)) ^ (cc & 15)) << 3) | ((q & 1) * 4))]);
                o[ct][0] = MFMA16K16(vf, pexp[g][0], o[ct][0]);
                o[ct][1] = MFMA16K16(vf, pexp[g][1], o[ct][1]);
            }
        }
        // q-tile bookkeeping (flush uses registers + global stores only; no LDS hazard)
        const int nqb = (k < 17) ? ((s*18 + k + 1) >> 6) : -1;
        if (nqb != cur_qb){
            flush(cur_qb);
            if (nqb >= 0){ load_q(nqb); zero_acc(); cur_qb = nqb; }
        }
    }
}

// ---------------- K3: combine partials, @Wo+bo, geo-gate, +feat0, transpose --------
__global__ __launch_bounds__(256) void k_out(
    const u16* __restrict__ Opart, const float* __restrict__ Lp,
    const float* __restrict__ bo, const u16* __restrict__ Wt,
    const u16* __restrict__ Gb, const float* __restrict__ feat0,
    float* __restrict__ outp)
{
    __shared__ __attribute__((aligned(16))) u16 AO[128*128];   // 32 KB
    __shared__ u16 Tr[128*130];                                 // 33.3 KB
    const int t = threadIdx.x;
    const int bqt = blockIdx.x;                 // 0..143 (half q-tiles of 128 rows)
    const int qt2 = bqt >> 1, half = bqt & 1;
    const int b = qt2 / 9, qb = qt2 % 9;
    const int gr0 = qb*256 + half*128;          // row base within batch
    const u16* WoT = Wt + 49152;
    const float rsC = 0.088388347648318447f;    // 1/sqrt(128)
    const int sf = (qb*64) / 18;
    const int sl = (qb*64 + 63) / 18;
    const int cnt = sl - sf + 1;
    for (int idx = t; idx < 128*128; idx += 256){
        int r = idx >> 7, c = idx & 127;
        float num = 0.f, den = 0.f;
        for (int ss = 0; ss < cnt; ss++){
            const size_t base = ((size_t)qt2*5 + ss)*256 + half*128 + r;
            num += bf2f(Opart[base*128 + c]);
            den += Lp[base];
        }
        AO[swz(r, c)] = f2bf(num / den * rsC);
    }
    __syncthreads();
    const int lane = t & 63, w = t >> 6;
    const int q = lane >> 4, m = lane & 15;
    const int rw = w * 32;
    f32x4 acc[2][8];
    #pragma unroll
    for (int rt = 0; rt < 2; rt++){
        #pragma unroll
        for (int ct = 0; ct < 8; ct++) acc[rt][ct] = fzero();
    }
    #pragma unroll
    for (int kt = 0; kt < 4; kt++){
        s16x8 a0, a1;
        { const int ar = rw + m;      a0 = ldsf(&AO[ar*128 + (((kt*4 + q) ^ (ar & 15)) << 3)]); }
        { const int ar = rw + 16 + m; a1 = ldsf(&AO[ar*128 + (((kt*4 + q) ^ (ar & 15)) << 3)]); }
        #pragma unroll
        for (int ct = 0; ct < 8; ct++){
            const s16x8 bb = *(const s16x8*)&WoT[(ct*16 + m)*128 + kt*32 + q*8];
            acc[0][ct] = mfma16(a0, bb, acc[0][ct]);
            acc[1][ct] = mfma16(a1, bb, acc[1][ct]);
        }
    }
    #pragma unroll
    for (int ct = 0; ct < 8; ct++){
        const int col = ct*16 + m;
        const float bov = bo[col];
        #pragma unroll
        for (int rt = 0; rt < 2; rt++){
            #pragma unroll
            for (int i = 0; i < 4; i++){
                const int rl = rw + rt*16 + q*4 + i;
                const float gv = bf2f(Gb[((size_t)b*WH_ + gr0 + rl)*C_ + col]);
                const float sg = 1.f / (1.f + __expf(-gv));
                Tr[rl*130 + col] = f2bf((acc[rt][ct][i] + bov) * (1.f + sg));
            }
        }
    }
    __syncthreads();
    for (int idx = t; idx < 128*128; idx += 256){
        int c = idx >> 7, wh = idx & 127;
        float v = bf2f(Tr[wh*130 + c]) + feat0[(size_t)(b*C_ + c)*WH_ + gr0 + wh];
        outp[(size_t)(b*C_ + c)*WH_ + gr0 + wh] = v;
    }
}

extern "C" void kernel_launch(void* const* d_in, const int* in_sizes, int n_in,
                              void* d_out, int out_size, void* d_ws, size_t ws_size,
                              hipStream_t stream)
{
    (void)in_sizes; (void)n_in; (void)out_size; (void)ws_size;
    const float* feat0 = (const float*)d_in[0];
    const float* feat1 = (const float*)d_in[1];
    const float* geo   = (const float*)d_in[2];
    const float* Wq = (const float*)d_in[3];  const float* bq = (const float*)d_in[4];
    const float* Wk = (const float*)d_in[5];  const float* bk = (const float*)d_in[6];
    const float* Wv = (const float*)d_in[7];  const float* bv = (const float*)d_in[8];
    const float* Wo = (const float*)d_in[9];  const float* bo = (const float*)d_in[10];
    const float* Wg = (const float*)d_in[11]; const float* bg = (const float*)d_in[12];
    const float* Wgate = (const float*)d_in[13]; const float* bgate = (const float*)d_in[14];
    float* outp = (float*)d_out;
    char* ws = (char*)d_ws;
    size_t off = 0;
    auto alloc = [&](size_t bytes) -> void* {
        void* p = (void*)(ws + off);
        off += (bytes + 255) & ~(size_t)255;
        return p;
    };
    u16* Qb = (u16*)alloc((size_t)B_*WH_*C_*2);         // pq (gated, x log2e)
    u16* Gb = (u16*)alloc((size_t)B_*WH_*C_*2);         // geo proj
    u16* Kb = (u16*)alloc((size_t)B_*N_*C_*2);          // pk [b][n][c]
    u16* Vb = (u16*)alloc((size_t)B_*N_*C_*2);          // pv^T [b][c][n]
    u16* Opart = (u16*)alloc((size_t)72*5*256*128*2);   // flash partials [q][c]
    float* Lp  = (float*)alloc((size_t)72*5*256*4);     // partial row sums
    u16* Wt = (u16*)alloc((size_t)5*16384*2);           // bf16 transposed weights

    k_prep   <<<dim3(320), dim3(256), 0, stream>>>(Wq, Wk, Wv, Wo, Wg, Wt);
    k_proj_kv<<<dim3(256), dim3(256), 0, stream>>>(feat1, bk, bv, Wt, Kb, Vb);
    k_proj_qg<<<dim3(144), dim3(256), 0, stream>>>(feat0, geo, bq, bg, Wgate, bgate, Wt, Qb, Gb);
    k_flash  <<<dim3(256), dim3(512), 0, stream>>>(Qb, Kb, Vb, Opart, Lp);
    k_out    <<<dim3(144), dim3(256), 0, stream>>>(Opart, Lp, bo, Wt, Gb, feat0, outp);
}